// Round 6
// baseline (14493.999 us; speedup 1.0000x reference)
//
#include <hip/hip_runtime.h>
#include <hip/hip_bf16.h>
#include <math.h>

#define Bb 64
#define Tt 1024
#define Dd 128
#define Hh 256
#define G4 1024  // 4*H
#define Vv 128
#define NVh 3
#define BT (Bb*Tt)

typedef __fp16 half2_t __attribute__((ext_vector_type(2)));

__device__ __forceinline__ half2_t pkh(float a, float b) {
    return __builtin_amdgcn_cvt_pkrtz(a, b);
}
__device__ __forceinline__ float fdot2(half2_t a, half2_t b, float c) {
#if __has_builtin(__builtin_amdgcn_fdot2)
    return __builtin_amdgcn_fdot2(a, b, c, false);
#else
    return c + (float)a[0] * (float)b[0] + (float)a[1] * (float)b[1];
#endif
}
__device__ __forceinline__ half2_t bch(unsigned int x) {
    return __builtin_bit_cast(half2_t, x);
}

// ---------------- Kernel A: gx[bt][j] = sum_d x[bt][d]*W_ih[j][d] + b_ih[j] + b_hh[j] ----
__global__ __launch_bounds__(256) void gx_gemm(const float* __restrict__ x,
                                               const float* __restrict__ Wih,
                                               const float* __restrict__ bih,
                                               const float* __restrict__ bhh,
                                               float* __restrict__ gx) {
    __shared__ float As[64][68];
    __shared__ float Ws[64][68];
    const int tid = threadIdx.x;
    const int tx = tid & 15, ty = tid >> 4;
    const int rb = blockIdx.x * 64;
    const int jb = blockIdx.y * 64;
    float acc[4][4] = {};
    for (int kb = 0; kb < Dd; kb += 64) {
        #pragma unroll
        for (int q = 0; q < 4; ++q) {
            int lin = q * 256 + tid;
            int row = lin >> 4;
            int c4 = (lin & 15) * 4;
            *(float4*)&As[row][c4] = *(const float4*)&x[(size_t)(rb + row) * Dd + kb + c4];
            *(float4*)&Ws[row][c4] = *(const float4*)&Wih[(size_t)(jb + row) * Dd + kb + c4];
        }
        __syncthreads();
        #pragma unroll 8
        for (int kk = 0; kk < 64; ++kk) {
            float a0 = As[ty*4+0][kk], a1 = As[ty*4+1][kk];
            float a2 = As[ty*4+2][kk], a3 = As[ty*4+3][kk];
            float w0 = Ws[tx*4+0][kk], w1 = Ws[tx*4+1][kk];
            float w2 = Ws[tx*4+2][kk], w3 = Ws[tx*4+3][kk];
            acc[0][0] += a0*w0; acc[0][1] += a0*w1; acc[0][2] += a0*w2; acc[0][3] += a0*w3;
            acc[1][0] += a1*w0; acc[1][1] += a1*w1; acc[1][2] += a1*w2; acc[1][3] += a1*w3;
            acc[2][0] += a2*w0; acc[2][1] += a2*w1; acc[2][2] += a2*w2; acc[2][3] += a2*w3;
            acc[3][0] += a3*w0; acc[3][1] += a3*w1; acc[3][2] += a3*w2; acc[3][3] += a3*w3;
        }
        __syncthreads();
    }
    const int col = jb + tx * 4;
    float bv0 = bih[col+0] + bhh[col+0];
    float bv1 = bih[col+1] + bhh[col+1];
    float bv2 = bih[col+2] + bhh[col+2];
    float bv3 = bih[col+3] + bhh[col+3];
    #pragma unroll
    for (int i = 0; i < 4; ++i) {
        int row = rb + ty * 4 + i;
        float4 r;
        r.x = acc[i][0] + bv0;
        r.y = acc[i][1] + bv1;
        r.z = acc[i][2] + bv2;
        r.w = acc[i][3] + bv3;
        *(float4*)&gx[(size_t)row * G4 + col] = r;
    }
}

// ---------------- Kernel B: persistent LSTM scan (v5) ------------------------------
// 64 blocks x 256 threads (4 waves, 1 wave/SIMD -> 512 unified regs/wave).
// Thread j owns ALL FOUR gate rows of h-index j: {j, j+256, j+512, j+768}.
//   pairs [0,116)  per row: 4 x 116 = 464 packed-f16 pairs in registers
//                  (compiler splits arch-VGPR / AGPR; AGPR reads are cheap VALU)
//   pairs [116,128) per row: 48KB LDS, lane-contiguous uint4 (conflict-free)
// h broadcast: 32 b128 LDS reads/thread/step; 4 waves -> 176 LDS ops/CU/step
// (was 384 in round 4). Gate update is fully thread-local: NO exchange.
__global__ __launch_bounds__(256, 1) void lstm_scan(const float* __restrict__ gx,
                                                    const float* __restrict__ Whh,
                                                    float* __restrict__ hs) {
    __shared__ __align__(16) uint4 wlds[12 * 256];   // 48KB: chunk r*3+q, lane j
    __shared__ __align__(16) __fp16 hsh[Hh];         // 512B
    const int j = threadIdx.x;
    const int b = blockIdx.x;

    // ---- stage W rows {j, j+256, j+512, j+768} ----
    half2_t w[4][116];
    #pragma unroll
    for (int r = 0; r < 4; ++r) {
        const float* wr = Whh + (size_t)(j + r * 256) * Hh;
        #pragma unroll
        for (int c = 0; c < 29; ++c) {          // elems [0,232): 116 pairs in regs
            float4 f0 = *(const float4*)&wr[c * 8];
            float4 f1 = *(const float4*)&wr[c * 8 + 4];
            w[r][c*4+0] = pkh(f0.x, f0.y);
            w[r][c*4+1] = pkh(f0.z, f0.w);
            w[r][c*4+2] = pkh(f1.x, f1.y);
            w[r][c*4+3] = pkh(f1.z, f1.w);
        }
        #pragma unroll
        for (int q = 0; q < 3; ++q) {           // elems [232,256): 12 pairs in LDS
            float4 f0 = *(const float4*)&wr[232 + q * 8];
            float4 f1 = *(const float4*)&wr[232 + q * 8 + 4];
            uint4 o;
            o.x = __builtin_bit_cast(unsigned int, pkh(f0.x, f0.y));
            o.y = __builtin_bit_cast(unsigned int, pkh(f0.z, f0.w));
            o.z = __builtin_bit_cast(unsigned int, pkh(f1.x, f1.y));
            o.w = __builtin_bit_cast(unsigned int, pkh(f1.z, f1.w));
            wlds[(r * 3 + q) * 256 + j] = o;
        }
    }
    if (j < 128) ((unsigned int*)hsh)[j] = 0u;
    float c_state = 0.f;
    __syncthreads();

    const float* gxb = gx + (size_t)b * Tt * G4 + j;
    float* hsb = hs + (size_t)b * Tt * Hh + j;

    float g0 = gxb[0], g1 = gxb[256], g2 = gxb[512], g3 = gxb[768];

    for (int t = 0; t < Tt; ++t) {
        // prefetch next step's gx (independent of h)
        const float* gn = gxb + (size_t)(t + 1 < Tt ? t + 1 : t) * G4;
        float n0 = gn[0], n1 = gn[256], n2 = gn[512], n3 = gn[768];

        float a0 = g0, a1 = g1, a2 = g2, a3 = g3;
        const uint4* h4 = (const uint4*)hsh;

        #pragma unroll
        for (int c = 0; c < 29; ++c) {
            uint4 hv = h4[c];                       // uniform broadcast read
            half2_t u0 = bch(hv.x), u1 = bch(hv.y);
            half2_t u2 = bch(hv.z), u3 = bch(hv.w);
            a0 = fdot2(w[0][c*4+0], u0, a0); a1 = fdot2(w[1][c*4+0], u0, a1);
            a2 = fdot2(w[2][c*4+0], u0, a2); a3 = fdot2(w[3][c*4+0], u0, a3);
            a0 = fdot2(w[0][c*4+1], u1, a0); a1 = fdot2(w[1][c*4+1], u1, a1);
            a2 = fdot2(w[2][c*4+1], u1, a2); a3 = fdot2(w[3][c*4+1], u1, a3);
            a0 = fdot2(w[0][c*4+2], u2, a0); a1 = fdot2(w[1][c*4+2], u2, a1);
            a2 = fdot2(w[2][c*4+2], u2, a2); a3 = fdot2(w[3][c*4+2], u2, a3);
            a0 = fdot2(w[0][c*4+3], u3, a0); a1 = fdot2(w[1][c*4+3], u3, a1);
            a2 = fdot2(w[2][c*4+3], u3, a2); a3 = fdot2(w[3][c*4+3], u3, a3);
        }
        // pairs [116,128): weights from LDS (lane-distinct, conflict-free)
        #pragma unroll
        for (int q = 0; q < 3; ++q) {
            uint4 hv = h4[29 + q];
            half2_t u0 = bch(hv.x), u1 = bch(hv.y);
            half2_t u2 = bch(hv.z), u3 = bch(hv.w);
            uint4 w0v = wlds[(0 * 3 + q) * 256 + j];
            uint4 w1v = wlds[(1 * 3 + q) * 256 + j];
            uint4 w2v = wlds[(2 * 3 + q) * 256 + j];
            uint4 w3v = wlds[(3 * 3 + q) * 256 + j];
            a0 = fdot2(bch(w0v.x), u0, a0); a1 = fdot2(bch(w1v.x), u0, a1);
            a2 = fdot2(bch(w2v.x), u0, a2); a3 = fdot2(bch(w3v.x), u0, a3);
            a0 = fdot2(bch(w0v.y), u1, a0); a1 = fdot2(bch(w1v.y), u1, a1);
            a2 = fdot2(bch(w2v.y), u1, a2); a3 = fdot2(bch(w3v.y), u1, a3);
            a0 = fdot2(bch(w0v.z), u2, a0); a1 = fdot2(bch(w1v.z), u2, a1);
            a2 = fdot2(bch(w2v.z), u2, a2); a3 = fdot2(bch(w3v.z), u2, a3);
            a0 = fdot2(bch(w0v.w), u3, a0); a1 = fdot2(bch(w1v.w), u3, a1);
            a2 = fdot2(bch(w2v.w), u3, a2); a3 = fdot2(bch(w3v.w), u3, a3);
        }

        // fully thread-local gate update (gate order i, f, g, o)
        float si = 1.f / (1.f + __expf(-a0));
        float sf = 1.f / (1.f + __expf(-a1));
        float tg = tanhf(a2);
        float so = 1.f / (1.f + __expf(-a3));
        c_state = sf * c_state + si * tg;
        float hn = so * tanhf(c_state);

        __syncthreads();                 // all hsh reads for step t complete
        hsh[j] = (__fp16)hn;
        hsb[(size_t)t * Hh] = hn;
        g0 = n0; g1 = n1; g2 = n2; g3 = n3;
        __syncthreads();                 // h(t) visible for step t+1
    }
}

// ---------------- Kernel C: logits[n][bt][v] = sum_h hs[bt][h]*head_w[n][v][h] + head_b[n][v]
__global__ __launch_bounds__(256) void head_gemm(const float* __restrict__ hs,
                                                 const float* __restrict__ hw,
                                                 const float* __restrict__ hb,
                                                 float* __restrict__ out) {
    __shared__ float As[64][68];
    __shared__ float Ws[64][68];
    const int tid = threadIdx.x;
    const int tx = tid & 15, ty = tid >> 4;
    const int rb = blockIdx.x * 64;
    const int cb = blockIdx.y * 64;
    float acc[4][4] = {};
    for (int kb = 0; kb < Hh; kb += 64) {
        #pragma unroll
        for (int q = 0; q < 4; ++q) {
            int lin = q * 256 + tid;
            int row = lin >> 4;
            int c4 = (lin & 15) * 4;
            *(float4*)&As[row][c4] = *(const float4*)&hs[(size_t)(rb + row) * Hh + kb + c4];
            *(float4*)&Ws[row][c4] = *(const float4*)&hw[(size_t)(cb + row) * Hh + kb + c4];
        }
        __syncthreads();
        #pragma unroll 8
        for (int kk = 0; kk < 64; ++kk) {
            float a0 = As[ty*4+0][kk], a1 = As[ty*4+1][kk];
            float a2 = As[ty*4+2][kk], a3 = As[ty*4+3][kk];
            float w0 = Ws[tx*4+0][kk], w1 = Ws[tx*4+1][kk];
            float w2 = Ws[tx*4+2][kk], w3 = Ws[tx*4+3][kk];
            acc[0][0] += a0*w0; acc[0][1] += a0*w1; acc[0][2] += a0*w2; acc[0][3] += a0*w3;
            acc[1][0] += a1*w0; acc[1][1] += a1*w1; acc[1][2] += a1*w2; acc[1][3] += a1*w3;
            acc[2][0] += a2*w0; acc[2][1] += a2*w1; acc[2][2] += a2*w2; acc[2][3] += a2*w3;
            acc[3][0] += a3*w0; acc[3][1] += a3*w1; acc[3][2] += a3*w2; acc[3][3] += a3*w3;
        }
        __syncthreads();
    }
    const int n = cb >> 7;
    const int v = (cb & 127) + tx * 4;
    float bv0 = hb[n*Vv + v + 0];
    float bv1 = hb[n*Vv + v + 1];
    float bv2 = hb[n*Vv + v + 2];
    float bv3 = hb[n*Vv + v + 3];
    #pragma unroll
    for (int i = 0; i < 4; ++i) {
        int row = rb + ty * 4 + i;
        float4 r;
        r.x = acc[i][0] + bv0;
        r.y = acc[i][1] + bv1;
        r.z = acc[i][2] + bv2;
        r.w = acc[i][3] + bv3;
        *(float4*)&out[(size_t)n * BT * Vv + (size_t)row * Vv + v] = r;
    }
}

extern "C" void kernel_launch(void* const* d_in, const int* in_sizes, int n_in,
                              void* d_out, int out_size, void* d_ws, size_t ws_size,
                              hipStream_t stream) {
    const float* x    = (const float*)d_in[0];
    const float* Wih  = (const float*)d_in[1];
    const float* Whh  = (const float*)d_in[2];
    const float* bih  = (const float*)d_in[3];
    const float* bhh  = (const float*)d_in[4];
    const float* hw   = (const float*)d_in[5];
    const float* hb   = (const float*)d_in[6];
    float* out = (float*)d_out;

    float* gxw = (float*)d_ws;                         // [BT][1024] f32 = 256 MB
    float* hsw = gxw + (size_t)BT * G4;                // [BT][256]  f32 =  64 MB

    gx_gemm<<<dim3(BT/64, G4/64), 256, 0, stream>>>(x, Wih, bih, bhh, gxw);
    lstm_scan<<<Bb, 256, 0, stream>>>(gxw, Whh, hsw);
    head_gemm<<<dim3(BT/64, (NVh*Vv)/64), 256, 0, stream>>>(hsw, hw, hb, out);
}

// Round 7
// 2255.166 us; speedup vs baseline: 6.4270x; 6.4270x over previous
//
#include <hip/hip_runtime.h>
#include <hip/hip_bf16.h>
#include <math.h>

#define Bb 64
#define Tt 1024
#define Dd 128
#define Hh 256
#define G4 1024  // 4*H
#define Vv 128
#define NVh 3
#define BT (Bb*Tt)

typedef __fp16 half2_t __attribute__((ext_vector_type(2)));

__device__ __forceinline__ half2_t pkh(float a, float b) {
    return __builtin_amdgcn_cvt_pkrtz(a, b);
}
__device__ __forceinline__ float fdot2(half2_t a, half2_t b, float c) {
#if __has_builtin(__builtin_amdgcn_fdot2)
    return __builtin_amdgcn_fdot2(a, b, c, false);
#else
    return c + (float)a[0] * (float)b[0] + (float)a[1] * (float)b[1];
#endif
}
__device__ __forceinline__ half2_t bch(unsigned int x) {
    return __builtin_bit_cast(half2_t, x);
}

// ---------------- Kernel A: gx[bt][j] = sum_d x[bt][d]*W_ih[j][d] + b_ih[j] + b_hh[j] ----
__global__ __launch_bounds__(256) void gx_gemm(const float* __restrict__ x,
                                               const float* __restrict__ Wih,
                                               const float* __restrict__ bih,
                                               const float* __restrict__ bhh,
                                               float* __restrict__ gx) {
    __shared__ float As[64][68];
    __shared__ float Ws[64][68];
    const int tid = threadIdx.x;
    const int tx = tid & 15, ty = tid >> 4;
    const int rb = blockIdx.x * 64;
    const int jb = blockIdx.y * 64;
    float acc[4][4] = {};
    for (int kb = 0; kb < Dd; kb += 64) {
        #pragma unroll
        for (int q = 0; q < 4; ++q) {
            int lin = q * 256 + tid;
            int row = lin >> 4;
            int c4 = (lin & 15) * 4;
            *(float4*)&As[row][c4] = *(const float4*)&x[(size_t)(rb + row) * Dd + kb + c4];
            *(float4*)&Ws[row][c4] = *(const float4*)&Wih[(size_t)(jb + row) * Dd + kb + c4];
        }
        __syncthreads();
        #pragma unroll 8
        for (int kk = 0; kk < 64; ++kk) {
            float a0 = As[ty*4+0][kk], a1 = As[ty*4+1][kk];
            float a2 = As[ty*4+2][kk], a3 = As[ty*4+3][kk];
            float w0 = Ws[tx*4+0][kk], w1 = Ws[tx*4+1][kk];
            float w2 = Ws[tx*4+2][kk], w3 = Ws[tx*4+3][kk];
            acc[0][0] += a0*w0; acc[0][1] += a0*w1; acc[0][2] += a0*w2; acc[0][3] += a0*w3;
            acc[1][0] += a1*w0; acc[1][1] += a1*w1; acc[1][2] += a1*w2; acc[1][3] += a1*w3;
            acc[2][0] += a2*w0; acc[2][1] += a2*w1; acc[2][2] += a2*w2; acc[2][3] += a2*w3;
            acc[3][0] += a3*w0; acc[3][1] += a3*w1; acc[3][2] += a3*w2; acc[3][3] += a3*w3;
        }
        __syncthreads();
    }
    const int col = jb + tx * 4;
    float bv0 = bih[col+0] + bhh[col+0];
    float bv1 = bih[col+1] + bhh[col+1];
    float bv2 = bih[col+2] + bhh[col+2];
    float bv3 = bih[col+3] + bhh[col+3];
    #pragma unroll
    for (int i = 0; i < 4; ++i) {
        int row = rb + ty * 4 + i;
        float4 r;
        r.x = acc[i][0] + bv0;
        r.y = acc[i][1] + bv1;
        r.z = acc[i][2] + bv2;
        r.w = acc[i][3] + bv3;
        *(float4*)&gx[(size_t)row * G4 + col] = r;
    }
}

// ---------------- Kernel B: persistent LSTM scan (v6: round-4 base + K-split S=2) ----
// 64 blocks x 512 threads (8 waves, 2/SIMD -> 256 unified regs/thread).
// Thread tid: jj = tid&255, s = tid>>8 (K-half). Owns ALL FOUR gate rows of
// h-index jj {jj, jj+256, jj+512, jj+768} restricted to K-half s (64 pairs each):
//   gates i,f,g: 3 x 64 = 192 packed-f16 pairs in regs (same footprint as round 4)
//   gate  o    : 64 pairs in LDS (128KB, lane-contiguous uint4, conflict-free)
// h-broadcast: 16 b128/thread (half of round 4). Partial-sum exchange: s=1
// writes one float4/thread, s=0 reads it -> update fully local on s=0 threads.
// LDS wave-ops/CU/step ~268 (was ~390 in round 4).
__global__ __launch_bounds__(512, 2) void lstm_scan(const float* __restrict__ gx,
                                                    const float* __restrict__ Whh,
                                                    float* __restrict__ hs) {
    __shared__ __align__(16) uint4 wlds[16 * 512];   // 128KB: [q][tid]
    __shared__ __align__(16) __fp16 hsh[Hh];         // 512B
    __shared__ __align__(16) float4 pex[256];        // 4KB: s=1 partials
    const int tid = threadIdx.x;
    const int jj = tid & 255;
    const int s = tid >> 8;            // wave-uniform (waves 0-3: s=0, 4-7: s=1)
    const int b = blockIdx.x;

    // ---- stage W: gates 0..2 (i,f,g) K-half s into regs; gate 3 (o) into LDS ----
    half2_t w[3][64];
    #pragma unroll
    for (int g = 0; g < 3; ++g) {
        const float* wr = Whh + (size_t)(g * 256 + jj) * Hh + s * 128;
        #pragma unroll
        for (int c = 0; c < 16; ++c) {
            float4 f0 = *(const float4*)&wr[c * 8];
            float4 f1 = *(const float4*)&wr[c * 8 + 4];
            w[g][c*4+0] = pkh(f0.x, f0.y);
            w[g][c*4+1] = pkh(f0.z, f0.w);
            w[g][c*4+2] = pkh(f1.x, f1.y);
            w[g][c*4+3] = pkh(f1.z, f1.w);
        }
    }
    {
        const float* wr3 = Whh + (size_t)(3 * 256 + jj) * Hh + s * 128;
        #pragma unroll
        for (int q = 0; q < 16; ++q) {
            float4 f0 = *(const float4*)&wr3[q * 8];
            float4 f1 = *(const float4*)&wr3[q * 8 + 4];
            uint4 o;
            o.x = __builtin_bit_cast(unsigned int, pkh(f0.x, f0.y));
            o.y = __builtin_bit_cast(unsigned int, pkh(f0.z, f0.w));
            o.z = __builtin_bit_cast(unsigned int, pkh(f1.x, f1.y));
            o.w = __builtin_bit_cast(unsigned int, pkh(f1.z, f1.w));
            wlds[q * 512 + tid] = o;
        }
    }
    if (tid < 128) ((unsigned int*)hsh)[tid] = 0u;
    float c_state = 0.f;
    __syncthreads();

    const float* gxb = gx + (size_t)b * Tt * G4 + jj;   // s=0 only
    float* hsb = hs + (size_t)b * Tt * Hh + jj;         // s=0 only

    float g0 = 0.f, g1 = 0.f, g2 = 0.f, g3 = 0.f;
    if (s == 0) { g0 = gxb[0]; g1 = gxb[256]; g2 = gxb[512]; g3 = gxb[768]; }

    const uint4* h4 = (const uint4*)hsh + (s << 4);     // 16 uint4 per K-half

    for (int t = 0; t < Tt; ++t) {
        // prefetch next step's gx (independent of h; s=0 waves only, uniform branch)
        float n0 = 0.f, n1 = 0.f, n2 = 0.f, n3 = 0.f;
        if (s == 0) {
            const float* gn = gxb + (size_t)(t + 1 < Tt ? t + 1 : t) * G4;
            n0 = gn[0]; n1 = gn[256]; n2 = gn[512]; n3 = gn[768];
        }

        float a0 = 0.f, a1 = 0.f, a2 = 0.f, a3 = 0.f;

        #pragma unroll
        for (int q = 0; q < 16; ++q) {
            uint4 hv = h4[q];                     // uniform broadcast read (K-half)
            uint4 wv = wlds[q * 512 + tid];       // lane-distinct, conflict-free
            half2_t u0 = bch(hv.x), u1 = bch(hv.y);
            half2_t u2 = bch(hv.z), u3 = bch(hv.w);
            a0 = fdot2(w[0][q*4+0], u0, a0); a1 = fdot2(w[1][q*4+0], u0, a1);
            a2 = fdot2(w[2][q*4+0], u0, a2); a3 = fdot2(bch(wv.x), u0, a3);
            a0 = fdot2(w[0][q*4+1], u1, a0); a1 = fdot2(w[1][q*4+1], u1, a1);
            a2 = fdot2(w[2][q*4+1], u1, a2); a3 = fdot2(bch(wv.y), u1, a3);
            a0 = fdot2(w[0][q*4+2], u2, a0); a1 = fdot2(w[1][q*4+2], u2, a1);
            a2 = fdot2(w[2][q*4+2], u2, a2); a3 = fdot2(bch(wv.z), u2, a3);
            a0 = fdot2(w[0][q*4+3], u3, a0); a1 = fdot2(w[1][q*4+3], u3, a1);
            a2 = fdot2(w[2][q*4+3], u3, a2); a3 = fdot2(bch(wv.w), u3, a3);
        }

        if (s == 1) pex[jj] = make_float4(a0, a1, a2, a3);
        __syncthreads();                 // pex visible; all hsh reads complete

        if (s == 0) {
            float4 pp = pex[jj];
            float A0 = a0 + pp.x + g0;   // gate i
            float A1 = a1 + pp.y + g1;   // gate f
            float A2 = a2 + pp.z + g2;   // gate g
            float A3 = a3 + pp.w + g3;   // gate o
            float si = 1.f / (1.f + __expf(-A0));
            float sf = 1.f / (1.f + __expf(-A1));
            float tg = tanhf(A2);
            float so = 1.f / (1.f + __expf(-A3));
            c_state = sf * c_state + si * tg;
            float hn = so * tanhf(c_state);
            hsh[jj] = (__fp16)hn;
            hsb[(size_t)t * Hh] = hn;
        }
        g0 = n0; g1 = n1; g2 = n2; g3 = n3;
        __syncthreads();                 // h(t) visible for step t+1
    }
}

// ---------------- Kernel C: logits[n][bt][v] = sum_h hs[bt][h]*head_w[n][v][h] + head_b[n][v]
__global__ __launch_bounds__(256) void head_gemm(const float* __restrict__ hs,
                                                 const float* __restrict__ hw,
                                                 const float* __restrict__ hb,
                                                 float* __restrict__ out) {
    __shared__ float As[64][68];
    __shared__ float Ws[64][68];
    const int tid = threadIdx.x;
    const int tx = tid & 15, ty = tid >> 4;
    const int rb = blockIdx.x * 64;
    const int cb = blockIdx.y * 64;
    float acc[4][4] = {};
    for (int kb = 0; kb < Hh; kb += 64) {
        #pragma unroll
        for (int q = 0; q < 4; ++q) {
            int lin = q * 256 + tid;
            int row = lin >> 4;
            int c4 = (lin & 15) * 4;
            *(float4*)&As[row][c4] = *(const float4*)&hs[(size_t)(rb + row) * Hh + kb + c4];
            *(float4*)&Ws[row][c4] = *(const float4*)&hw[(size_t)(cb + row) * Hh + kb + c4];
        }
        __syncthreads();
        #pragma unroll 8
        for (int kk = 0; kk < 64; ++kk) {
            float a0 = As[ty*4+0][kk], a1 = As[ty*4+1][kk];
            float a2 = As[ty*4+2][kk], a3 = As[ty*4+3][kk];
            float w0 = Ws[tx*4+0][kk], w1 = Ws[tx*4+1][kk];
            float w2 = Ws[tx*4+2][kk], w3 = Ws[tx*4+3][kk];
            acc[0][0] += a0*w0; acc[0][1] += a0*w1; acc[0][2] += a0*w2; acc[0][3] += a0*w3;
            acc[1][0] += a1*w0; acc[1][1] += a1*w1; acc[1][2] += a1*w2; acc[1][3] += a1*w3;
            acc[2][0] += a2*w0; acc[2][1] += a2*w1; acc[2][2] += a2*w2; acc[2][3] += a2*w3;
            acc[3][0] += a3*w0; acc[3][1] += a3*w1; acc[3][2] += a3*w2; acc[3][3] += a3*w3;
        }
        __syncthreads();
    }
    const int n = cb >> 7;
    const int v = (cb & 127) + tx * 4;
    float bv0 = hb[n*Vv + v + 0];
    float bv1 = hb[n*Vv + v + 1];
    float bv2 = hb[n*Vv + v + 2];
    float bv3 = hb[n*Vv + v + 3];
    #pragma unroll
    for (int i = 0; i < 4; ++i) {
        int row = rb + ty * 4 + i;
        float4 r;
        r.x = acc[i][0] + bv0;
        r.y = acc[i][1] + bv1;
        r.z = acc[i][2] + bv2;
        r.w = acc[i][3] + bv3;
        *(float4*)&out[(size_t)n * BT * Vv + (size_t)row * Vv + v] = r;
    }
}

extern "C" void kernel_launch(void* const* d_in, const int* in_sizes, int n_in,
                              void* d_out, int out_size, void* d_ws, size_t ws_size,
                              hipStream_t stream) {
    const float* x    = (const float*)d_in[0];
    const float* Wih  = (const float*)d_in[1];
    const float* Whh  = (const float*)d_in[2];
    const float* bih  = (const float*)d_in[3];
    const float* bhh  = (const float*)d_in[4];
    const float* hw   = (const float*)d_in[5];
    const float* hb   = (const float*)d_in[6];
    float* out = (float*)d_out;

    float* gxw = (float*)d_ws;                         // [BT][1024] f32 = 256 MB
    float* hsw = gxw + (size_t)BT * G4;                // [BT][256]  f32 =  64 MB

    gx_gemm<<<dim3(BT/64, G4/64), 256, 0, stream>>>(x, Wih, bih, bhh, gxw);
    lstm_scan<<<Bb, 512, 0, stream>>>(gxw, Whh, hsw);
    head_gemm<<<dim3(BT/64, (NVh*Vv)/64), 256, 0, stream>>>(hsw, hw, hb, out);
}

// Round 8
// 1768.126 us; speedup vs baseline: 8.1974x; 1.2755x over previous
//
#include <hip/hip_runtime.h>
#include <hip/hip_bf16.h>
#include <math.h>

#define Bb 64
#define Tt 1024
#define Dd 128
#define Hh 256
#define G4 1024  // 4*H
#define Vv 128
#define NVh 3
#define BT (Bb*Tt)

typedef __fp16 half2_t __attribute__((ext_vector_type(2)));
typedef __fp16 f16x4 __attribute__((ext_vector_type(4)));
typedef __fp16 f16x8 __attribute__((ext_vector_type(8)));
typedef float f32x4 __attribute__((ext_vector_type(4)));

__device__ __forceinline__ half2_t pkh(float a, float b) {
    return __builtin_amdgcn_cvt_pkrtz(a, b);
}
__device__ __forceinline__ float fdot2(half2_t a, half2_t b, float c) {
#if __has_builtin(__builtin_amdgcn_fdot2)
    return __builtin_amdgcn_fdot2(a, b, c, false);
#else
    return c + (float)a[0] * (float)b[0] + (float)a[1] * (float)b[1];
#endif
}
__device__ __forceinline__ half2_t bch(unsigned int x) {
    return __builtin_bit_cast(half2_t, x);
}
__device__ __forceinline__ float fsig(float x) {
    return __builtin_amdgcn_rcpf(1.f + __expf(-x));
}
__device__ __forceinline__ float ftanh(float x) {
    float e = __expf(-2.f * fabsf(x));
    float r = (1.f - e) * __builtin_amdgcn_rcpf(1.f + e);
    return copysignf(r, x);
}

// ---------------- Kernel 0: f32 -> f16 convert (RNE), n multiple of 4 ----------
__global__ __launch_bounds__(256) void cvt16(const float* __restrict__ in,
                                             __fp16* __restrict__ out, int n4) {
    int i = blockIdx.x * 256 + threadIdx.x;
    if (i < n4) {
        float4 v = ((const float4*)in)[i];
        f16x4 o;
        o[0] = (__fp16)v.x; o[1] = (__fp16)v.y;
        o[2] = (__fp16)v.z; o[3] = (__fp16)v.w;
        ((f16x4*)out)[i] = o;
    }
}

// ---------------- Kernel A: gx via MFMA f16 -------------------------------------
// gx2[bt][jj][gate] (f16x4 packed) = x[bt][:]·W_ih[gate*256+jj][:] + b_ih + b_hh
// Block 256 thr = 4 waves; wave w: M-subtile mb=bx*64+w*16, all waves share jj0.
// Per wave: 4 N-tiles = the SAME jj range across the 4 gates -> epilogue packs
// i,f,g,o for one (bt,jj) into one 8B store (coalesced).
__global__ __launch_bounds__(256) void gx_mfma(const __fp16* __restrict__ x16,
                                               const __fp16* __restrict__ Wih16,
                                               const float* __restrict__ bih,
                                               const float* __restrict__ bhh,
                                               __fp16* __restrict__ gx2) {
    const int tid = threadIdx.x;
    const int w = tid >> 6, l = tid & 63;
    const int mb = blockIdx.x * 64 + w * 16;
    const int jj0 = blockIdx.y * 16;
    const int lr = l & 15, lk = l >> 4;

    f32x4 acc[4] = {};
    const __fp16* xa = x16 + (size_t)(mb + lr) * Dd + lk * 8;
    #pragma unroll
    for (int ks = 0; ks < 4; ++ks) {                 // K=128, 32 per step
        f16x8 af = *(const f16x8*)(xa + ks * 32);
        #pragma unroll
        for (int g = 0; g < 4; ++g) {
            const __fp16* bb = Wih16 + (size_t)(g * 256 + jj0 + lr) * Dd + ks * 32 + lk * 8;
            f16x8 bf = *(const f16x8*)bb;
            acc[g] = __builtin_amdgcn_mfma_f32_16x16x32_f16(af, bf, acc[g], 0, 0, 0);
        }
    }
    float bsum[4];
    #pragma unroll
    for (int g = 0; g < 4; ++g) {
        int j = g * 256 + jj0 + lr;
        bsum[g] = bih[j] + bhh[j];
    }
    #pragma unroll
    for (int r = 0; r < 4; ++r) {
        int m = mb + lk * 4 + r;                     // D row = (lane>>4)*4+reg
        f16x4 o;
        o[0] = (__fp16)(acc[0][r] + bsum[0]);
        o[1] = (__fp16)(acc[1][r] + bsum[1]);
        o[2] = (__fp16)(acc[2][r] + bsum[2]);
        o[3] = (__fp16)(acc[3][r] + bsum[3]);
        *(f16x4*)&gx2[((size_t)m * Hh + jj0 + lr) * 4] = o;
    }
}

// ---------------- Kernel B: persistent LSTM scan (v7) ---------------------------
// Structure = round 7 (512 thr, K-split S=2, W: 192 pairs regs + 64 pairs LDS).
// New: gx read as one 8B f16x4 load; h store deferred one step (keeps vmcnt
// empty at barrier-2); branch-free fast activations; hs stored f16.
__global__ __launch_bounds__(512, 2) void lstm_scan(const __fp16* __restrict__ gx2,
                                                    const float* __restrict__ Whh,
                                                    __fp16* __restrict__ hs16) {
    __shared__ __align__(16) uint4 wlds[16 * 512];   // 128KB: [q][tid]
    __shared__ __align__(16) __fp16 hsh[Hh];         // 512B
    __shared__ __align__(16) float4 pex[256];        // 4KB: s=1 partials
    const int tid = threadIdx.x;
    const int jj = tid & 255;
    const int s = tid >> 8;            // wave-uniform (waves 0-3: s=0, 4-7: s=1)
    const int b = blockIdx.x;

    // ---- stage W: gates i,f,g K-half s into regs; gate o into LDS ----
    half2_t w[3][64];
    #pragma unroll
    for (int g = 0; g < 3; ++g) {
        const float* wr = Whh + (size_t)(g * 256 + jj) * Hh + s * 128;
        #pragma unroll
        for (int c = 0; c < 16; ++c) {
            float4 f0 = *(const float4*)&wr[c * 8];
            float4 f1 = *(const float4*)&wr[c * 8 + 4];
            w[g][c*4+0] = pkh(f0.x, f0.y);
            w[g][c*4+1] = pkh(f0.z, f0.w);
            w[g][c*4+2] = pkh(f1.x, f1.y);
            w[g][c*4+3] = pkh(f1.z, f1.w);
        }
    }
    {
        const float* wr3 = Whh + (size_t)(3 * 256 + jj) * Hh + s * 128;
        #pragma unroll
        for (int q = 0; q < 16; ++q) {
            float4 f0 = *(const float4*)&wr3[q * 8];
            float4 f1 = *(const float4*)&wr3[q * 8 + 4];
            uint4 o;
            o.x = __builtin_bit_cast(unsigned int, pkh(f0.x, f0.y));
            o.y = __builtin_bit_cast(unsigned int, pkh(f0.z, f0.w));
            o.z = __builtin_bit_cast(unsigned int, pkh(f1.x, f1.y));
            o.w = __builtin_bit_cast(unsigned int, pkh(f1.z, f1.w));
            wlds[q * 512 + tid] = o;
        }
    }
    if (tid < 128) ((unsigned int*)hsh)[tid] = 0u;
    float c_state = 0.f;
    __syncthreads();

    const __fp16* gxb = gx2 + ((size_t)b * Tt * Hh + jj) * 4;  // step stride 1024 f16
    __fp16* hsb = hs16 + (size_t)b * Tt * Hh + jj;             // s=0 only

    float g0 = 0.f, g1 = 0.f, g2 = 0.f, g3 = 0.f;
    if (s == 0) {
        uint2 gv = *(const uint2*)gxb;
        half2_t p = bch(gv.x), q = bch(gv.y);
        g0 = (float)p[0]; g1 = (float)p[1]; g2 = (float)q[0]; g3 = (float)q[1];
    }

    const uint4* h4 = (const uint4*)hsh + (s << 4);  // 16 uint4 per K-half
    __fp16 hprev = (__fp16)0.f;

    for (int t = 0; t < Tt; ++t) {
        // deferred h store from step t-1 (hidden by the q-loop; drained at barrier-1)
        if (s == 0 && t > 0) hsb[(size_t)(t - 1) * Hh] = hprev;

        // prefetch next step's gx (independent of h; s=0 waves only, uniform branch)
        float n0 = 0.f, n1 = 0.f, n2 = 0.f, n3 = 0.f;
        if (s == 0) {
            const __fp16* gn = gxb + (size_t)(t + 1 < Tt ? t + 1 : t) * 1024;
            uint2 gv = *(const uint2*)gn;
            half2_t p = bch(gv.x), q = bch(gv.y);
            n0 = (float)p[0]; n1 = (float)p[1]; n2 = (float)q[0]; n3 = (float)q[1];
        }

        float a0 = 0.f, a1 = 0.f, a2 = 0.f, a3 = 0.f;

        #pragma unroll
        for (int q = 0; q < 16; ++q) {
            uint4 hv = h4[q];                     // uniform broadcast read (K-half)
            uint4 wv = wlds[q * 512 + tid];       // lane-distinct, conflict-free
            half2_t u0 = bch(hv.x), u1 = bch(hv.y);
            half2_t u2 = bch(hv.z), u3 = bch(hv.w);
            a0 = fdot2(w[0][q*4+0], u0, a0); a1 = fdot2(w[1][q*4+0], u0, a1);
            a2 = fdot2(w[2][q*4+0], u0, a2); a3 = fdot2(bch(wv.x), u0, a3);
            a0 = fdot2(w[0][q*4+1], u1, a0); a1 = fdot2(w[1][q*4+1], u1, a1);
            a2 = fdot2(w[2][q*4+1], u1, a2); a3 = fdot2(bch(wv.y), u1, a3);
            a0 = fdot2(w[0][q*4+2], u2, a0); a1 = fdot2(w[1][q*4+2], u2, a1);
            a2 = fdot2(w[2][q*4+2], u2, a2); a3 = fdot2(bch(wv.z), u2, a3);
            a0 = fdot2(w[0][q*4+3], u3, a0); a1 = fdot2(w[1][q*4+3], u3, a1);
            a2 = fdot2(w[2][q*4+3], u3, a2); a3 = fdot2(bch(wv.w), u3, a3);
        }

        if (s == 1) pex[jj] = make_float4(a0, a1, a2, a3);
        __syncthreads();                 // pex visible; all hsh reads complete

        if (s == 0) {
            float4 pp = pex[jj];
            float A0 = a0 + pp.x + g0;   // gate i
            float A1 = a1 + pp.y + g1;   // gate f
            float A2 = a2 + pp.z + g2;   // gate g
            float A3 = a3 + pp.w + g3;   // gate o
            float si = fsig(A0);
            float sf = fsig(A1);
            float tg = ftanh(A2);
            float so = fsig(A3);
            c_state = sf * c_state + si * tg;
            float hn = so * ftanh(c_state);
            hprev = (__fp16)hn;
            hsh[jj] = hprev;
        }
        g0 = n0; g1 = n1; g2 = n2; g3 = n3;
        __syncthreads();                 // h(t) visible for step t+1
    }
    if (s == 0) hsb[(size_t)(Tt - 1) * Hh] = hprev;
}

// ---------------- Kernel C: head via MFMA f16 -----------------------------------
// out[n][bt][v] = hs16[bt][:]·hw16[n*128+v][:] + hb[n][v]
__global__ __launch_bounds__(256) void head_mfma(const __fp16* __restrict__ hs16,
                                                 const __fp16* __restrict__ hw16,
                                                 const float* __restrict__ hb,
                                                 float* __restrict__ out) {
    const int tid = threadIdx.x;
    const int w = tid >> 6, l = tid & 63;
    const int mb = blockIdx.x * 64 + w * 16;
    const int n0 = blockIdx.y * 64;                  // 4 N-tiles of 16
    const int lr = l & 15, lk = l >> 4;

    f32x4 acc[4] = {};
    const __fp16* aa = hs16 + (size_t)(mb + lr) * Hh + lk * 8;
    #pragma unroll
    for (int ks = 0; ks < 8; ++ks) {                 // K=256, 32 per step
        f16x8 af = *(const f16x8*)(aa + ks * 32);
        #pragma unroll
        for (int nt = 0; nt < 4; ++nt) {
            const __fp16* bb = hw16 + (size_t)(n0 + nt * 16 + lr) * Hh + ks * 32 + lk * 8;
            f16x8 bf = *(const f16x8*)bb;
            acc[nt] = __builtin_amdgcn_mfma_f32_16x16x32_f16(af, bf, acc[nt], 0, 0, 0);
        }
    }
    #pragma unroll
    for (int nt = 0; nt < 4; ++nt) {
        int nv = n0 + nt * 16 + lr;
        int nh = nv >> 7, v = nv & 127;
        float bv = hb[nv];
        #pragma unroll
        for (int r = 0; r < 4; ++r) {
            int m = mb + lk * 4 + r;
            out[(size_t)nh * BT * Vv + (size_t)m * Vv + v] = acc[nt][r] + bv;
        }
    }
}

extern "C" void kernel_launch(void* const* d_in, const int* in_sizes, int n_in,
                              void* d_out, int out_size, void* d_ws, size_t ws_size,
                              hipStream_t stream) {
    const float* x    = (const float*)d_in[0];
    const float* Wih  = (const float*)d_in[1];
    const float* Whh  = (const float*)d_in[2];
    const float* bih  = (const float*)d_in[3];
    const float* bhh  = (const float*)d_in[4];
    const float* hw   = (const float*)d_in[5];
    const float* hb   = (const float*)d_in[6];
    float* out = (float*)d_out;

    // workspace carve (f16): x16 | Wih16 | hw16 | gx2 | hs16  (~176 MB total)
    __fp16* x16   = (__fp16*)d_ws;                     // BT*128
    __fp16* Wih16 = x16 + (size_t)BT * Dd;             // 1024*128
    __fp16* hw16  = Wih16 + (size_t)G4 * Dd;           // 384*256
    __fp16* gx2   = hw16 + (size_t)NVh * Vv * Hh;      // BT*1024 (packed f16x4)
    __fp16* hs16  = gx2 + (size_t)BT * G4;             // BT*256

    cvt16<<<(BT * Dd / 4 + 255) / 256, 256, 0, stream>>>(x, x16, BT * Dd / 4);
    cvt16<<<(G4 * Dd / 4 + 255) / 256, 256, 0, stream>>>(Wih, Wih16, G4 * Dd / 4);
    cvt16<<<(NVh * Vv * Hh / 4 + 255) / 256, 256, 0, stream>>>(hw, hw16, NVh * Vv * Hh / 4);

    gx_mfma<<<dim3(BT / 64, Hh / 16), 256, 0, stream>>>(x16, Wih16, bih, bhh, gx2);
    lstm_scan<<<Bb, 512, 0, stream>>>(gx2, Whh, hs16);
    head_mfma<<<dim3(BT / 64, (NVh * Vv) / 64), 256, 0, stream>>>(hs16, hw16, hb, out);
}